// Round 2
// baseline (135.653 us; speedup 1.0000x reference)
//
#include <hip/hip_runtime.h>
#include <math.h>

#define HW (512*512)
#define TS 64
#define HRY 70    // tile rows + 2*3 halo
#define LSTR 76   // LDS row stride: 18 aligned quads (cc 0..71 used) + pad

// ---------------- Kernel 1: per-plane partial sums (global avg pool) ----------------
__global__ __launch_bounds__(256) void k_reduce(const float* __restrict__ x,
                                                float* __restrict__ ws) {
    int bid = blockIdx.x;            // 1024 blocks = 128 planes * 8 chunks
    int plane = bid >> 3, j = bid & 7;
    const float4* xv = (const float4*)x + (size_t)plane * 65536 + (size_t)j * 8192;
    int tid = threadIdx.x;
    float s = 0.f;
    #pragma unroll
    for (int k = 0; k < 32; ++k) {
        float4 v = xv[(size_t)k * 256 + tid];
        s += (v.x + v.y) + (v.z + v.w);
    }
    #pragma unroll
    for (int off = 32; off > 0; off >>= 1) s += __shfl_down(s, off, 64);
    __shared__ float red[4];
    if ((tid & 63) == 0) red[tid >> 6] = s;
    __syncthreads();
    if (tid == 0) ws[bid] = (red[0] + red[1]) + (red[2] + red[3]);
}

// ---------------- Kernel 2: finish pool + channel-attention MLP ----------------
__global__ __launch_bounds__(128) void k_mlp(const float* __restrict__ part,
                                             const float* __restrict__ w1,
                                             const float* __restrict__ b1,
                                             const float* __restrict__ w2,
                                             const float* __restrict__ b2,
                                             float* __restrict__ att_out) {
    __shared__ float pool[128];   // [b][c], b=32, c=4
    __shared__ float hbuf[64];    // [b][r], r=2
    int tid = threadIdx.x;
    float s = 0.f;
    #pragma unroll
    for (int j = 0; j < 8; ++j) s += part[tid * 8 + j];
    pool[tid] = s * (1.f / 262144.f);
    __syncthreads();
    if (tid < 64) {
        int b = tid >> 1, r = tid & 1;
        float h = b1[r];
        #pragma unroll
        for (int c = 0; c < 4; ++c) h += w1[r * 4 + c] * pool[b * 4 + c];
        hbuf[tid] = fmaxf(h, 0.f);          // hbuf[b*2+r]
    }
    __syncthreads();
    {
        int b = tid >> 2, c = tid & 3;
        float z = b2[c];
        #pragma unroll
        for (int r = 0; r < 2; ++r) z += w2[c * 2 + r] * hbuf[b * 2 + r];
        att_out[tid] = 1.f / (1.f + __expf(-z));   // att[b*4+c]
    }
}

// ---------------- Kernel 3: fused gate + 1x1 conv + 7x7 conv + sigmoid gate ----------------
// Tile 64x64 out px per block (256 thr). Thread owns 4x4 px: tx4=tid&15 -> cols
// 4*tx4..+3, tyg=tid>>4 -> rows 4*tyg..+3. All LDS/global traffic is b128.
// LDS col index cc = gx - tx0 + 4, so cc quads (cc0 % 4 == 0) map to ALIGNED
// global quads (gx0 = tx0-4+cc0, tx0%64==0). 512%4==0 => every quad is fully
// in-bounds or fully out -> no partial masking.
__global__ __launch_bounds__(256) void k_fused(const float* __restrict__ x,
                                               const float* __restrict__ conv_w,
                                               const float* __restrict__ conv_b,
                                               const float* __restrict__ sa_w,
                                               const float* __restrict__ sa_b,
                                               const float* __restrict__ att,
                                               float* __restrict__ out) {
    __shared__ float s_out[3 * HRY * LSTR];   // 63,840 B
    int tid = threadIdx.x;
    int b = blockIdx.z;
    int ty0 = blockIdx.y * TS, tx0 = blockIdx.x * TS;

    // uniform params (scalar loads)
    float kw[12], kb[3];
    #pragma unroll
    for (int t = 0; t < 12; ++t) kw[t] = conv_w[t] * att[b * 4 + (t & 3)];
    #pragma unroll
    for (int o = 0; o < 3; ++o) kb[o] = conv_b[o];
    float sbias = sa_b[0];

    // ---- Stage: gated 1x1 conv for tile+halo into LDS, float4 granularity ----
    const float* xb = x + (size_t)b * 4 * HW;
    for (int idx = tid; idx < HRY * 18; idx += 256) {
        int r = idx / 18, q = idx - r * 18;
        int cc0 = q * 4;
        int gy = ty0 - 3 + r;
        int gx0 = tx0 - 4 + cc0;
        float4 o0 = make_float4(0.f, 0.f, 0.f, 0.f), o1 = o0, o2 = o0;
        if ((unsigned)gy < 512u && (unsigned)gx0 <= 508u) {
            size_t off = (size_t)gy * 512 + gx0;
            float4 X0 = *(const float4*)(xb + off);
            float4 X1 = *(const float4*)(xb + HW + off);
            float4 X2 = *(const float4*)(xb + 2 * HW + off);
            float4 X3 = *(const float4*)(xb + 3 * HW + off);
#define DO1(comp) \
            o0.comp = kb[0] + kw[0]*X0.comp + kw[1]*X1.comp + kw[2]*X2.comp + kw[3]*X3.comp; \
            o1.comp = kb[1] + kw[4]*X0.comp + kw[5]*X1.comp + kw[6]*X2.comp + kw[7]*X3.comp; \
            o2.comp = kb[2] + kw[8]*X0.comp + kw[9]*X1.comp + kw[10]*X2.comp + kw[11]*X3.comp;
            DO1(x) DO1(y) DO1(z) DO1(w)
#undef DO1
        }
        float* sp = &s_out[r * LSTR + cc0];
        *(float4*)(sp)                  = o0;
        *(float4*)(sp + HRY * LSTR)     = o1;
        *(float4*)(sp + 2 * HRY * LSTR) = o2;
    }
    __syncthreads();

    // ---- 7x7 conv: thread computes 4x4 outputs; 3 b128 LDS reads per input row ----
    int tx4 = tid & 15, tyg = tid >> 4;
    int cbase = tx4 * 4;
    float acc[4][4] = {{0.f}};

    #pragma unroll
    for (int ch = 0; ch < 3; ++ch) {
        const float* sbp = &s_out[ch * HRY * LSTR];
        const float* wp = sa_w + ch * 49;
        #pragma unroll
        for (int k = 0; k < 10; ++k) {
            const float* row = sbp + (tyg * 4 + k) * LSTR + cbase;
            float4 va = *(const float4*)(row);
            float4 vb = *(const float4*)(row + 4);
            float4 vc = *(const float4*)(row + 8);
            float v[12] = {va.x, va.y, va.z, va.w,
                           vb.x, vb.y, vb.z, vb.w,
                           vc.x, vc.y, vc.z, vc.w};
            #pragma unroll
            for (int dy = 0; dy < 7; ++dy) {
                int i = k - dy;
                if (i >= 0 && i < 4) {
                    #pragma unroll
                    for (int dx = 0; dx < 7; ++dx) {
                        float wv = wp[dy * 7 + dx];   // uniform -> s_load
                        #pragma unroll
                        for (int j = 0; j < 4; ++j)
                            acc[i][j] += wv * v[j + dx + 1];
                    }
                }
            }
        }
    }

    // ---- Epilogue: sigmoid gate + b128 stores ----
    float* ob = out + (size_t)b * 3 * HW;
    #pragma unroll
    for (int i = 0; i < 4; ++i) {
        int oy = tyg * 4 + i;
        const float* rp = &s_out[(oy + 3) * LSTR + cbase + 4];
        float4 c0 = *(const float4*)(rp);
        float4 c1 = *(const float4*)(rp + HRY * LSTR);
        float4 c2 = *(const float4*)(rp + 2 * HRY * LSTR);
        float g0 = 1.f / (1.f + __expf(-(acc[i][0] + sbias)));
        float g1 = 1.f / (1.f + __expf(-(acc[i][1] + sbias)));
        float g2 = 1.f / (1.f + __expf(-(acc[i][2] + sbias)));
        float g3 = 1.f / (1.f + __expf(-(acc[i][3] + sbias)));
        c0.x *= g0; c0.y *= g1; c0.z *= g2; c0.w *= g3;
        c1.x *= g0; c1.y *= g1; c1.z *= g2; c1.w *= g3;
        c2.x *= g0; c2.y *= g1; c2.z *= g2; c2.w *= g3;
        size_t off = (size_t)(ty0 + oy) * 512 + (tx0 + cbase);
        *(float4*)(ob + off)          = c0;
        *(float4*)(ob + HW + off)     = c1;
        *(float4*)(ob + 2 * HW + off) = c2;
    }
}

extern "C" void kernel_launch(void* const* d_in, const int* in_sizes, int n_in,
                              void* d_out, int out_size, void* d_ws, size_t ws_size,
                              hipStream_t stream) {
    const float* x      = (const float*)d_in[0];
    const float* ca_w1  = (const float*)d_in[1];
    const float* ca_b1  = (const float*)d_in[2];
    const float* ca_w2  = (const float*)d_in[3];
    const float* ca_b2  = (const float*)d_in[4];
    const float* conv_w = (const float*)d_in[5];
    const float* conv_b = (const float*)d_in[6];
    const float* sa_w   = (const float*)d_in[7];
    const float* sa_b   = (const float*)d_in[8];
    float* ws  = (float*)d_ws;
    float* out = (float*)d_out;

    hipLaunchKernelGGL(k_reduce, dim3(1024), dim3(256), 0, stream, x, ws);
    hipLaunchKernelGGL(k_mlp, dim3(1), dim3(128), 0, stream,
                       ws, ca_w1, ca_b1, ca_w2, ca_b2, ws + 1024);
    hipLaunchKernelGGL(k_fused, dim3(8, 8, 32), dim3(256), 0, stream,
                       x, conv_w, conv_b, sa_w, sa_b, ws + 1024, out);
}

// Round 3
// 94.752 us; speedup vs baseline: 1.4317x; 1.4317x over previous
//
#include <hip/hip_runtime.h>
#include <math.h>

#define HW (512*512)
#define TSX 64
#define TSY 32
#define NROW 38              // TSY + 6 halo rows
#define LSTR 80              // dwords per LDS row (20 quads; logical quads 0..17, swizzled <=18)
#define CH_STRIDE (NROW*LSTR)

// ---------------- Kernel 1: per-plane partial sums (global avg pool) ----------------
__global__ __launch_bounds__(256) void k_reduce(const float* __restrict__ x,
                                                float* __restrict__ ws) {
    int bid = blockIdx.x;            // 1024 blocks = 128 planes * 8 chunks
    int plane = bid >> 3, j = bid & 7;
    const float4* xv = (const float4*)x + (size_t)plane * 65536 + (size_t)j * 8192;
    int tid = threadIdx.x;
    float s = 0.f;
    #pragma unroll
    for (int k = 0; k < 32; ++k) {
        float4 v = xv[(size_t)k * 256 + tid];
        s += (v.x + v.y) + (v.z + v.w);
    }
    #pragma unroll
    for (int off = 32; off > 0; off >>= 1) s += __shfl_down(s, off, 64);
    __shared__ float red[4];
    if ((tid & 63) == 0) red[tid >> 6] = s;
    __syncthreads();
    if (tid == 0) ws[bid] = (red[0] + red[1]) + (red[2] + red[3]);
}

// ---------------- Kernel 2: finish pool + channel-attention MLP ----------------
__global__ __launch_bounds__(128) void k_mlp(const float* __restrict__ part,
                                             const float* __restrict__ w1,
                                             const float* __restrict__ b1,
                                             const float* __restrict__ w2,
                                             const float* __restrict__ b2,
                                             float* __restrict__ att_out) {
    __shared__ float pool[128];   // [b][c], b=32, c=4
    __shared__ float hbuf[64];    // [b][r], r=2
    int tid = threadIdx.x;
    float s = 0.f;
    #pragma unroll
    for (int j = 0; j < 8; ++j) s += part[tid * 8 + j];
    pool[tid] = s * (1.f / 262144.f);
    __syncthreads();
    if (tid < 64) {
        int b = tid >> 1, r = tid & 1;
        float h = b1[r];
        #pragma unroll
        for (int c = 0; c < 4; ++c) h += w1[r * 4 + c] * pool[b * 4 + c];
        hbuf[tid] = fmaxf(h, 0.f);          // hbuf[b*2+r]
    }
    __syncthreads();
    {
        int b = tid >> 2, c = tid & 3;
        float z = b2[c];
        #pragma unroll
        for (int r = 0; r < 2; ++r) z += w2[c * 2 + r] * hbuf[b * 2 + r];
        att_out[tid] = 1.f / (1.f + __expf(-z));   // att[b*4+c]
    }
}

// ---------------- Kernel 3: fused gate + 1x1 conv + 7x7 conv + sigmoid gate ----------------
// Tile 64x32. 256 threads, thread owns 4 cols x 2 rows. LDS quad index is
// XOR-swizzled with key=(row>>1)&3 so the conv read (lanes span 4 row-groups,
// rows 2 apart) spreads across bank quartets (T2 pattern, write+read both swizzled).
__global__ __launch_bounds__(256, 4) void k_fused(const float* __restrict__ x,
                                                  const float* __restrict__ conv_w,
                                                  const float* __restrict__ conv_b,
                                                  const float* __restrict__ sa_w,
                                                  const float* __restrict__ sa_b,
                                                  const float* __restrict__ att,
                                                  float* __restrict__ out) {
    __shared__ float s_out[3 * CH_STRIDE];   // 36,480 B -> 4 blocks/CU
    int tid = threadIdx.x;
    int b = blockIdx.z;
    int ty0 = blockIdx.y * TSY, tx0 = blockIdx.x * TSX;

    // uniform params (scalar loads)
    float kw[12], kb[3];
    #pragma unroll
    for (int t = 0; t < 12; ++t) kw[t] = conv_w[t] * att[b * 4 + (t & 3)];
    #pragma unroll
    for (int o = 0; o < 3; ++o) kb[o] = conv_b[o];
    float sbias = sa_b[0];

    // ---- Stage: gated 1x1 conv for tile+halo into LDS (swizzled b128 writes) ----
    // logical: row r (0..37) = gy - (ty0-3); dword cc = gx - (tx0-4), quads q=0..17
    const float* xb = x + (size_t)b * 4 * HW;
    for (int idx = tid; idx < NROW * 18; idx += 256) {
        int r = idx / 18, q = idx - r * 18;
        int gy = ty0 - 3 + r;
        int gx0 = tx0 - 4 + q * 4;
        float4 o0 = make_float4(0.f, 0.f, 0.f, 0.f), o1 = o0, o2 = o0;
        if ((unsigned)gy < 512u && (unsigned)gx0 <= 508u) {
            size_t off = (size_t)gy * 512 + gx0;
            float4 X0 = *(const float4*)(xb + off);
            float4 X1 = *(const float4*)(xb + HW + off);
            float4 X2 = *(const float4*)(xb + 2 * HW + off);
            float4 X3 = *(const float4*)(xb + 3 * HW + off);
#define DO1(comp) \
            o0.comp = kb[0] + kw[0]*X0.comp + kw[1]*X1.comp + kw[2]*X2.comp + kw[3]*X3.comp; \
            o1.comp = kb[1] + kw[4]*X0.comp + kw[5]*X1.comp + kw[6]*X2.comp + kw[7]*X3.comp; \
            o2.comp = kb[2] + kw[8]*X0.comp + kw[9]*X1.comp + kw[10]*X2.comp + kw[11]*X3.comp;
            DO1(x) DO1(y) DO1(z) DO1(w)
#undef DO1
        }
        int base = r * LSTR + (((q ^ ((r >> 1) & 3)) << 2));
        *(float4*)(&s_out[base])                 = o0;
        *(float4*)(&s_out[base + CH_STRIDE])     = o1;
        *(float4*)(&s_out[base + 2 * CH_STRIDE]) = o2;
    }
    __syncthreads();

    // ---- 7x7 conv: thread computes 4 cols x 2 rows; 3 swizzled b128 reads / input row ----
    int tx4 = tid & 15, ty2 = tid >> 4;   // ty2 0..15 -> out rows 2*ty2, 2*ty2+1
    float acc[2][4] = {{0.f, 0.f, 0.f, 0.f}, {0.f, 0.f, 0.f, 0.f}};

    #pragma unroll
    for (int ch = 0; ch < 3; ++ch) {
        const float* sbp = &s_out[ch * CH_STRIDE];
        const float* wp = sa_w + ch * 49;
        #pragma unroll
        for (int k = 0; k < 8; ++k) {
            int lr = ty2 * 2 + k;            // logical row, 0..37
            int key = (lr >> 1) & 3;
            int rb = lr * LSTR;
            float4 va = *(const float4*)(sbp + rb + (((tx4    ) ^ key) << 2));
            float4 vb = *(const float4*)(sbp + rb + (((tx4 + 1) ^ key) << 2));
            float4 vc = *(const float4*)(sbp + rb + (((tx4 + 2) ^ key) << 2));
            float v[12] = {va.x, va.y, va.z, va.w,
                           vb.x, vb.y, vb.z, vb.w,
                           vc.x, vc.y, vc.z, vc.w};
            #pragma unroll
            for (int i = 0; i < 2; ++i) {
                int dy = k - i;
                if (dy >= 0 && dy <= 6) {
                    #pragma unroll
                    for (int dx = 0; dx < 7; ++dx) {
                        float wv = wp[dy * 7 + dx];   // uniform -> s_load
                        #pragma unroll
                        for (int j = 0; j < 4; ++j)
                            acc[i][j] += wv * v[j + dx + 1];
                    }
                }
            }
        }
    }

    // ---- Epilogue: sigmoid gate + b128 stores ----
    float* ob = out + (size_t)b * 3 * HW;
    #pragma unroll
    for (int i = 0; i < 2; ++i) {
        int oy = ty2 * 2 + i;                // 0..31
        int lr = oy + 3;                     // center row
        int key = (lr >> 1) & 3;
        int base = lr * LSTR + (((tx4 + 1) ^ key) << 2);
        float4 c0 = *(const float4*)(&s_out[base]);
        float4 c1 = *(const float4*)(&s_out[base + CH_STRIDE]);
        float4 c2 = *(const float4*)(&s_out[base + 2 * CH_STRIDE]);
        float g0 = 1.f / (1.f + __expf(-(acc[i][0] + sbias)));
        float g1 = 1.f / (1.f + __expf(-(acc[i][1] + sbias)));
        float g2 = 1.f / (1.f + __expf(-(acc[i][2] + sbias)));
        float g3 = 1.f / (1.f + __expf(-(acc[i][3] + sbias)));
        c0.x *= g0; c0.y *= g1; c0.z *= g2; c0.w *= g3;
        c1.x *= g0; c1.y *= g1; c1.z *= g2; c1.w *= g3;
        c2.x *= g0; c2.y *= g1; c2.z *= g2; c2.w *= g3;
        size_t off = (size_t)(ty0 + oy) * 512 + (tx0 + tx4 * 4);
        *(float4*)(ob + off)          = c0;
        *(float4*)(ob + HW + off)     = c1;
        *(float4*)(ob + 2 * HW + off) = c2;
    }
}

extern "C" void kernel_launch(void* const* d_in, const int* in_sizes, int n_in,
                              void* d_out, int out_size, void* d_ws, size_t ws_size,
                              hipStream_t stream) {
    const float* x      = (const float*)d_in[0];
    const float* ca_w1  = (const float*)d_in[1];
    const float* ca_b1  = (const float*)d_in[2];
    const float* ca_w2  = (const float*)d_in[3];
    const float* ca_b2  = (const float*)d_in[4];
    const float* conv_w = (const float*)d_in[5];
    const float* conv_b = (const float*)d_in[6];
    const float* sa_w   = (const float*)d_in[7];
    const float* sa_b   = (const float*)d_in[8];
    float* ws  = (float*)d_ws;
    float* out = (float*)d_out;

    hipLaunchKernelGGL(k_reduce, dim3(1024), dim3(256), 0, stream, x, ws);
    hipLaunchKernelGGL(k_mlp, dim3(1), dim3(128), 0, stream,
                       ws, ca_w1, ca_b1, ca_w2, ca_b2, ws + 1024);
    hipLaunchKernelGGL(k_fused, dim3(8, 16, 32), dim3(256), 0, stream,
                       x, conv_w, conv_b, sa_w, sa_b, ws + 1024, out);
}